// Round 18
// baseline (144.574 us; speedup 1.0000x reference)
//
#include <hip/hip_runtime.h>
#include <hip/hip_bf16.h>
#include <math.h>

#define N_TOK 2048
#define FEAT  768
#define HEADS 12
#define DHEAD 64
#define SPLIT 4
#define KV_PER (N_TOK / SPLIT)   // 512

typedef __bf16 v8bf __attribute__((ext_vector_type(8)));
typedef __bf16 v4bf __attribute__((ext_vector_type(4)));
typedef float  v4f  __attribute__((ext_vector_type(4)));

#define XE ((size_t)N_TOK * FEAT)   // 1572864
#define WE ((size_t)FEAT * FEAT)    //  589824
#define QK_LD 1536                  // [Q'|K] row stride

// fold (1/sqrt(64)) * log2(e) into Wq so softmax is a bare exp2
#define SCALE_FOLD 0.18033688011112042f

// async global->LDS, 16B/lane; LDS dest = wave-uniform base + lane*16 (m104)
__device__ __forceinline__ void gload16(const __bf16* g, __bf16* l) {
    __builtin_amdgcn_global_load_lds(
        (const __attribute__((address_space(1))) unsigned int*)g,
        (__attribute__((address_space(3))) unsigned int*)l, 16, 0, 0);
}

// ---------------------------------------------------------------- convert (1 launch)
__global__ __launch_bounds__(256) void cvt_all(
        const float* __restrict__ x,  const float* __restrict__ Wq,
        const float* __restrict__ Wk, const float* __restrict__ Wv,
        const float* __restrict__ Wo,
        __bf16* __restrict__ xb, __bf16* __restrict__ wqkv, __bf16* __restrict__ wob) {
    size_t i = ((size_t)blockIdx.x * 256 + threadIdx.x) * 4;
    const float* src; __bf16* dst; size_t off; float scale = 1.f;
    if (i < XE)               { src = x;  dst = xb;          off = i; }
    else if (i < XE + WE)     { src = Wq; dst = wqkv;        off = i - XE; scale = SCALE_FOLD; }
    else if (i < XE + 2 * WE) { src = Wk; dst = wqkv + WE;   off = i - XE - WE; }
    else if (i < XE + 3 * WE) { src = Wv; dst = wqkv + 2*WE; off = i - XE - 2*WE; }
    else                      { src = Wo; dst = wob;         off = i - XE - 3*WE; }
    float4 v = *(const float4*)(src + off);
    v4bf o;
    o[0] = (__bf16)(v.x * scale); o[1] = (__bf16)(v.y * scale);
    o[2] = (__bf16)(v.z * scale); o[3] = (__bf16)(v.w * scale);
    *(v4bf*)(dst + off) = o;
}

// ---------------------------------------------------------------- fused QKV GEMM (bf16, gload16)
// 64x128 tile, BK=64 (12 iters). Grid (18, 32) = 576. Global-side octet XOR swizzle.
// QK cols (bn<1536) -> qk row-major stride 1536; V cols -> vt transposed [768][2048].
__global__ __launch_bounds__(256) void gemm_qkv(
        const __bf16* __restrict__ A, const __bf16* __restrict__ B,
        __bf16* __restrict__ qk, __bf16* __restrict__ vt) {
    __shared__ __bf16 As[64][64];
    __shared__ __bf16 Bs[128][64];
    const int t    = threadIdx.x;
    const int lane = t & 63, w = t >> 6;
    const int quad = lane >> 4, l15 = lane & 15;
    const int wm = w & 1, wn = w >> 1;
    const int bm = blockIdx.y * 64, bn = blockIdx.x * 128;
    const int lr8 = lane >> 3;
    const int gs  = ((lane & 7) ^ lr8) * 8;    // global-side swizzle (rows = base8 + lr8)

    v4f acc[2][4] = {};
    for (int k0 = 0; k0 < FEAT; k0 += 64) {
        gload16(A + (size_t)(bm + w * 16 +      lr8) * FEAT + k0 + gs, &As[w * 16][0]);
        gload16(A + (size_t)(bm + w * 16 + 8 +  lr8) * FEAT + k0 + gs, &As[w * 16 + 8][0]);
        gload16(B + (size_t)(bn + w * 32 +      lr8) * FEAT + k0 + gs, &Bs[w * 32][0]);
        gload16(B + (size_t)(bn + w * 32 + 8 +  lr8) * FEAT + k0 + gs, &Bs[w * 32 + 8][0]);
        gload16(B + (size_t)(bn + w * 32 + 16 + lr8) * FEAT + k0 + gs, &Bs[w * 32 + 16][0]);
        gload16(B + (size_t)(bn + w * 32 + 24 + lr8) * FEAT + k0 + gs, &Bs[w * 32 + 24][0]);
        __syncthreads();
#pragma unroll
        for (int kk = 0; kk < 2; kk++) {
            const int fo = ((kk * 4 + quad) ^ (l15 & 7)) * 8;   // un-swizzled frag octet
            v8bf a[2], b[4];
#pragma unroll
            for (int mi = 0; mi < 2; mi++) a[mi] = *(const v8bf*)&As[wm * 32 + mi * 16 + l15][fo];
#pragma unroll
            for (int ni = 0; ni < 4; ni++) b[ni] = *(const v8bf*)&Bs[wn * 64 + ni * 16 + l15][fo];
#pragma unroll
            for (int mi = 0; mi < 2; mi++)
#pragma unroll
                for (int ni = 0; ni < 4; ni++)
                    acc[mi][ni] = __builtin_amdgcn_mfma_f32_16x16x32_bf16(a[mi], b[ni], acc[mi][ni], 0, 0, 0);
        }
        __syncthreads();
    }
    if (bn < 2 * FEAT) {         // Q,K region
#pragma unroll
        for (int mi = 0; mi < 2; mi++)
#pragma unroll
            for (int ni = 0; ni < 4; ni++) {
                int col = bn + wn * 64 + ni * 16 + l15;
#pragma unroll
                for (int r = 0; r < 4; r++) {
                    int row = bm + wm * 32 + mi * 16 + quad * 4 + r;
                    qk[(size_t)row * QK_LD + col] = (__bf16)acc[mi][ni][r];
                }
            }
    } else {                     // V region: transposed packed store vt[col-1536][row]
#pragma unroll
        for (int mi = 0; mi < 2; mi++)
#pragma unroll
            for (int ni = 0; ni < 4; ni++) {
                int col = bn + wn * 64 + ni * 16 + l15 - 2 * FEAT;
                int row = bm + wm * 32 + mi * 16 + quad * 4;
                v4bf pk;
#pragma unroll
                for (int r = 0; r < 4; r++) pk[r] = (__bf16)acc[mi][ni][r];
                *(v4bf*)(vt + (size_t)col * N_TOK + row) = pk;
            }
    }
}

// ---------------------------------------------------------------- attention v10 (S^T, V direct-global)
// v8 (R15 best) with V fragments loaded transiently from vt global at use (per-lane
// contiguous 16B; no persistent prefetch arrays -> no R16-style spill). K stays LDS-staged
// (shared across waves). LDS reads/tile: 20 -> 12 b128. LDS = 16 KB K + 8 KB PT = 24 KB.
// Grid (16, 12, SPLIT=4) = 768 blocks, 3/CU.
__global__ __launch_bounds__(256, 3) void attention(
        const __bf16* __restrict__ QK, const __bf16* __restrict__ vt,
        __bf16* __restrict__ Opart, float* __restrict__ lpart) {
    __shared__ __bf16 Ks[2][64][64];      // [buf][kv-row][d]  16 KB
    __shared__ __bf16 PT[4][32][32];      // per-wave P^T half: [w][q][kv32]  8 KB
    const int t    = threadIdx.x;
    const int lane = t & 63, w = t >> 6;
    const int quad = lane >> 4, l15 = lane & 15;
    const int h = blockIdx.y, s = blockIdx.z;
    const int q0 = blockIdx.x * 128 + w * 32;
    const int sw3 = l15 & 3;              // PT octet swizzle

    v8bf qf[2][2];
#pragma unroll
    for (int qt = 0; qt < 2; qt++) {
        const __bf16* qp = QK + (size_t)(q0 + qt * 16 + l15) * QK_LD + h * DHEAD + quad * 8;
        qf[qt][0] = *(const v8bf*)qp;
        qf[qt][1] = *(const v8bf*)(qp + 32);
    }
    const __bf16* kg = QK + FEAT + h * DHEAD;
    const __bf16* vg = vt + (size_t)(h * DHEAD + l15) * N_TOK + quad * 8;  // per-lane V base

    v4f o_acc[4][2] = {};                 // [dt][qt]: O^T rows d=quad*4+r, cols q
    float lacc[2] = {0.f, 0.f};

    const int kvbeg = s * KV_PER;
    const int lr8 = lane >> 3;

    auto stage_k = [&](int b, int kv0) {
#pragma unroll
        for (int i = 0; i < 2; i++) {
            int row = w * 16 + i * 8 + lr8;
            int gsk = (lane & 7) ^ (row & 7);              // global-side swizzle
            gload16(kg + (size_t)(kv0 + row) * QK_LD + gsk * 8, &Ks[b][w * 16 + i * 8][0]);
        }
    };

    auto step = [&](int b, int kv0) {
#pragma unroll
        for (int half = 0; half < 2; half++) {
            // ---- S^T for this half's 32 kv rows; exp; write P^T half
#pragma unroll
            for (int kk = 0; kk < 2; kk++) {
                int kvt = half * 2 + kk;
                v8bf kf0 = *(const v8bf*)&Ks[b][kvt * 16 + l15][((0 + quad) ^ (l15 & 7)) * 8];
                v8bf kf1 = *(const v8bf*)&Ks[b][kvt * 16 + l15][((4 + quad) ^ (l15 & 7)) * 8];
                const int wcol = ((kk * 2 + (quad >> 1)) ^ sw3) * 8 + (quad & 1) * 4;
#pragma unroll
                for (int qt = 0; qt < 2; qt++) {
                    v4f a = {};
                    a = __builtin_amdgcn_mfma_f32_16x16x32_bf16(kf0, qf[qt][0], a, 0, 0, 0);
                    a = __builtin_amdgcn_mfma_f32_16x16x32_bf16(kf1, qf[qt][1], a, 0, 0, 0);
                    float p0 = __builtin_amdgcn_exp2f(a[0]);
                    float p1 = __builtin_amdgcn_exp2f(a[1]);
                    float p2 = __builtin_amdgcn_exp2f(a[2]);
                    float p3 = __builtin_amdgcn_exp2f(a[3]);
                    lacc[qt] += (p0 + p1) + (p2 + p3);
                    v4bf pk;
                    pk[0] = (__bf16)p0; pk[1] = (__bf16)p1; pk[2] = (__bf16)p2; pk[3] = (__bf16)p3;
                    *(v4bf*)&PT[w][qt * 16 + l15][wcol] = pk;
                }
            }
            // ---- O^T += V^T_half P^T_half (k=32); V frags transient from global
            v8bf vf[4], ptf[2];
#pragma unroll
            for (int dt = 0; dt < 4; dt++)
                vf[dt] = *(const v8bf*)(vg + (size_t)(dt * 16) * N_TOK + kv0 + half * 32);
#pragma unroll
            for (int qt = 0; qt < 2; qt++)
                ptf[qt] = *(const v8bf*)&PT[w][qt * 16 + l15][(quad ^ sw3) * 8];
#pragma unroll
            for (int dt = 0; dt < 4; dt++)
#pragma unroll
                for (int qt = 0; qt < 2; qt++)
                    o_acc[dt][qt] = __builtin_amdgcn_mfma_f32_16x16x32_bf16(vf[dt], ptf[qt], o_acc[dt][qt], 0, 0, 0);
        }
    };

    stage_k(0, kvbeg);
    const int TILES = KV_PER / 64;     // 8
    for (int tt = 0; tt < TILES; tt++) {
        __syncthreads();               // K buf[tt&1] staged (vmcnt drain at barrier)
        if (tt + 1 < TILES) stage_k((tt + 1) & 1, kvbeg + (tt + 1) * 64);
        step(tt & 1, kvbeg + tt * 64);
    }

    // ---- epilogue: l-reduce over quads (2 shfls), packed b64 global stores
    __bf16* op = Opart + (size_t)s * XE;
#pragma unroll
    for (int qt = 0; qt < 2; qt++) {
        float l = lacc[qt];
        l += __shfl_xor(l, 16); l += __shfl_xor(l, 32);   // sum the 4 quads (same q)
        float linv = 1.0f / l;
        int q = q0 + qt * 16 + l15;
        if (quad == 0) lpart[((size_t)s * HEADS + h) * N_TOK + q] = l;
#pragma unroll
        for (int dt = 0; dt < 4; dt++) {
            v4bf pk;
#pragma unroll
            for (int r = 0; r < 4; r++) pk[r] = (__bf16)(o_acc[dt][qt][r] * linv);
            *(v4bf*)(op + (size_t)q * FEAT + h * DHEAD + dt * 16 + quad * 4) = pk;
        }
    }
}

// ---------------------------------------------------------------- combine split partials (one pass)
__global__ __launch_bounds__(256) void combine(
        const __bf16* __restrict__ Op, const float* __restrict__ lp, __bf16* __restrict__ Ob) {
    size_t i = ((size_t)blockIdx.x * 256 + threadIdx.x) * 4;
    int row = (int)(i / FEAT), col = (int)(i % FEAT), h = col >> 6;
    float ls[SPLIT], tot = 0.f;
#pragma unroll
    for (int s = 0; s < SPLIT; s++) {
        ls[s] = lp[((size_t)s * HEADS + h) * N_TOK + row];
        tot += ls[s];
    }
    float inv = 1.0f / tot;
    float a0 = 0.f, a1 = 0.f, a2 = 0.f, a3 = 0.f;
#pragma unroll
    for (int s = 0; s < SPLIT; s++) {
        v4bf p = *(const v4bf*)(Op + s * XE + i);
        float wgt = ls[s] * inv;
        a0 += wgt * (float)p[0]; a1 += wgt * (float)p[1];
        a2 += wgt * (float)p[2]; a3 += wgt * (float)p[3];
    }
    v4bf o;
    o[0] = (__bf16)a0; o[1] = (__bf16)a1; o[2] = (__bf16)a2; o[3] = (__bf16)a3;
    *(v4bf*)(Ob + i) = o;
}

// ---------------------------------------------------------------- output proj + residual (pure m97 GEMM)
__global__ __launch_bounds__(256) void gemm_out(
        const __bf16* __restrict__ Ob, const __bf16* __restrict__ Wo,
        const float* __restrict__ x, float* __restrict__ Yf) {
    __shared__ __bf16 As[64][32];
    __shared__ __bf16 Bs[128][32];
    const int t    = threadIdx.x;
    const int lane = t & 63, w = t >> 6;
    const int quad = lane >> 4, l15 = lane & 15;
    const int wm = w & 1, wn = w >> 1;
    const int bm = blockIdx.y * 64, bn = blockIdx.x * 128;
    const int srow = lane >> 2, scol = (lane & 3) * 8;

    v4f acc[2][4] = {};
    for (int k0 = 0; k0 < FEAT; k0 += 32) {
        gload16(Ob + (size_t)(bm + w * 16 + srow) * FEAT + k0 + scol,      &As[w * 16][0]);
        gload16(Wo + (size_t)(bn + w * 32 + srow) * FEAT + k0 + scol,      &Bs[w * 32][0]);
        gload16(Wo + (size_t)(bn + w * 32 + 16 + srow) * FEAT + k0 + scol, &Bs[w * 32 + 16][0]);
        __syncthreads();
        v8bf a[2], b[4];
#pragma unroll
        for (int mi = 0; mi < 2; mi++) a[mi] = *(const v8bf*)&As[wm * 32 + mi * 16 + l15][quad * 8];
#pragma unroll
        for (int ni = 0; ni < 4; ni++) b[ni] = *(const v8bf*)&Bs[wn * 64 + ni * 16 + l15][quad * 8];
#pragma unroll
        for (int mi = 0; mi < 2; mi++)
#pragma unroll
            for (int ni = 0; ni < 4; ni++)
                acc[mi][ni] = __builtin_amdgcn_mfma_f32_16x16x32_bf16(a[mi], b[ni], acc[mi][ni], 0, 0, 0);
        __syncthreads();
    }
#pragma unroll
    for (int mi = 0; mi < 2; mi++)
#pragma unroll
        for (int ni = 0; ni < 4; ni++) {
            int col = bn + wn * 64 + ni * 16 + l15;
#pragma unroll
            for (int r = 0; r < 4; r++) {
                int row = bm + wm * 32 + mi * 16 + quad * 4 + r;
                Yf[(size_t)row * FEAT + col] = acc[mi][ni][r] + x[(size_t)row * FEAT + col];
            }
        }
}

// ---------------------------------------------------------------- layernorm
__global__ __launch_bounds__(256) void ln_kernel(
        const float* __restrict__ Y, const float* __restrict__ gamma,
        const float* __restrict__ beta, float* __restrict__ out) {
    __shared__ float sbuf[4];
    const int row = blockIdx.x, t = threadIdx.x;
    const float* y = Y + (size_t)row * FEAT;
    float v0 = y[t], v1 = y[t + 256], v2 = y[t + 512];
    float s = v0 + v1 + v2;
#pragma unroll
    for (int m = 32; m; m >>= 1) s += __shfl_xor(s, m);
    if ((t & 63) == 0) sbuf[t >> 6] = s;
    __syncthreads();
    float mean = (sbuf[0] + sbuf[1] + sbuf[2] + sbuf[3]) * (1.f / FEAT);
    __syncthreads();
    float d0 = v0 - mean, d1 = v1 - mean, d2 = v2 - mean;
    float q = d0 * d0 + d1 * d1 + d2 * d2;
#pragma unroll
    for (int m = 32; m; m >>= 1) q += __shfl_xor(q, m);
    if ((t & 63) == 0) sbuf[t >> 6] = q;
    __syncthreads();
    float var = (sbuf[0] + sbuf[1] + sbuf[2] + sbuf[3]) * (1.f / FEAT);
    float rs = rsqrtf(var + 1e-12f);
    float* o = out + (size_t)row * FEAT;
    o[t]       = d0 * rs * gamma[t]       + beta[t];
    o[t + 256] = d1 * rs * gamma[t + 256] + beta[t + 256];
    o[t + 512] = d2 * rs * gamma[t + 512] + beta[t + 512];
}

// ---------------------------------------------------------------- launch
extern "C" void kernel_launch(void* const* d_in, const int* in_sizes, int n_in,
                              void* d_out, int out_size, void* d_ws, size_t ws_size,
                              hipStream_t stream) {
    const float* x     = (const float*)d_in[0];
    const float* Wq    = (const float*)d_in[1];
    const float* Wk    = (const float*)d_in[2];
    const float* Wv    = (const float*)d_in[3];
    const float* Wo    = (const float*)d_in[4];
    const float* gamma = (const float*)d_in[5];
    const float* beta  = (const float*)d_in[6];
    float* out = (float*)d_out;

    char* ws = (char*)d_ws;
    size_t off = 0;
    auto alloc = [&](size_t bytes) -> void* {
        void* p = ws + off;
        off += (bytes + 255) & ~(size_t)255;
        return p;
    };
    __bf16* xb   = (__bf16*)alloc(XE * 2);                    // dead after gemm_qkv
    __bf16* wqkv = (__bf16*)alloc(3 * WE * 2);                // dead after gemm_qkv
    __bf16* wob  = (__bf16*)alloc(WE * 2);
    __bf16* qk   = (__bf16*)alloc((size_t)N_TOK * QK_LD * 2); // [Q'|K]; dead after attention
    __bf16* vtb  = (__bf16*)alloc((size_t)FEAT * N_TOK * 2);  // V^T; dead after attention
    __bf16* Op   = (__bf16*)alloc(SPLIT * XE * 2);            // normalized split partials
    float*  lp   = (float*)alloc(SPLIT * HEADS * N_TOK * 4);
    __bf16* Ob   = vtb;                                       // aliases vt (dead by combine)
    float*  Yf   = (float*)ws;                                // aliases xb+wqkv (dead by gemm_out)

    cvt_all<<<(int)((XE + 4 * WE) / 4 / 256), 256, 0, stream>>>(x, Wq, Wk, Wv, Wo, xb, wqkv, wob);

    gemm_qkv<<<dim3((QK_LD + FEAT) / 128, N_TOK / 64), 256, 0, stream>>>(xb, wqkv, qk, vtb);

    attention<<<dim3(N_TOK / 128, HEADS, SPLIT), 256, 0, stream>>>(qk, vtb, Op, lp);

    combine<<<(int)(XE / 4 / 256), 256, 0, stream>>>(Op, lp, Ob);

    gemm_out<<<dim3(FEAT / 128, N_TOK / 64), 256, 0, stream>>>(Ob, wob, x, Yf);

    ln_kernel<<<N_TOK, 256, 0, stream>>>(Yf, gamma, beta, out);
}

// Round 19
// 135.448 us; speedup vs baseline: 1.0674x; 1.0674x over previous
//
#include <hip/hip_runtime.h>
#include <hip/hip_bf16.h>
#include <math.h>

#define N_TOK 2048
#define FEAT  768
#define HEADS 12
#define DHEAD 64
#define SPLIT 4
#define KV_PER (N_TOK / SPLIT)   // 512

typedef __bf16 v8bf __attribute__((ext_vector_type(8)));
typedef __bf16 v4bf __attribute__((ext_vector_type(4)));
typedef float  v4f  __attribute__((ext_vector_type(4)));

#define XE ((size_t)N_TOK * FEAT)   // 1572864
#define WE ((size_t)FEAT * FEAT)    //  589824
#define QK_LD 1536                  // [Q'|K] row stride

// fold (1/sqrt(64)) * log2(e) into Wq so softmax is a bare exp2
#define SCALE_FOLD 0.18033688011112042f

// async global->LDS, 16B/lane; LDS dest = wave-uniform base + lane*16 (m104)
__device__ __forceinline__ void gload16(const __bf16* g, __bf16* l) {
    __builtin_amdgcn_global_load_lds(
        (const __attribute__((address_space(1))) unsigned int*)g,
        (__attribute__((address_space(3))) unsigned int*)l, 16, 0, 0);
}

// ---------------------------------------------------------------- convert (1 launch)
__global__ __launch_bounds__(256) void cvt_all(
        const float* __restrict__ x,  const float* __restrict__ Wq,
        const float* __restrict__ Wk, const float* __restrict__ Wv,
        const float* __restrict__ Wo,
        __bf16* __restrict__ xb, __bf16* __restrict__ wqkv, __bf16* __restrict__ wob) {
    size_t i = ((size_t)blockIdx.x * 256 + threadIdx.x) * 4;
    const float* src; __bf16* dst; size_t off; float scale = 1.f;
    if (i < XE)               { src = x;  dst = xb;          off = i; }
    else if (i < XE + WE)     { src = Wq; dst = wqkv;        off = i - XE; scale = SCALE_FOLD; }
    else if (i < XE + 2 * WE) { src = Wk; dst = wqkv + WE;   off = i - XE - WE; }
    else if (i < XE + 3 * WE) { src = Wv; dst = wqkv + 2*WE; off = i - XE - 2*WE; }
    else                      { src = Wo; dst = wob;         off = i - XE - 3*WE; }
    float4 v = *(const float4*)(src + off);
    v4bf o;
    o[0] = (__bf16)(v.x * scale); o[1] = (__bf16)(v.y * scale);
    o[2] = (__bf16)(v.z * scale); o[3] = (__bf16)(v.w * scale);
    *(v4bf*)(dst + off) = o;
}

// ---------------------------------------------------------------- fused QKV GEMM (bf16, gload16)
// 64x128 tile, BK=64 (12 iters). Grid (18, 32) = 576. Global-side octet XOR swizzle.
// QK cols (bn<1536) -> qk row-major stride 1536; V cols -> vt transposed [768][2048].
__global__ __launch_bounds__(256) void gemm_qkv(
        const __bf16* __restrict__ A, const __bf16* __restrict__ B,
        __bf16* __restrict__ qk, __bf16* __restrict__ vt) {
    __shared__ __bf16 As[64][64];
    __shared__ __bf16 Bs[128][64];
    const int t    = threadIdx.x;
    const int lane = t & 63, w = t >> 6;
    const int quad = lane >> 4, l15 = lane & 15;
    const int wm = w & 1, wn = w >> 1;
    const int bm = blockIdx.y * 64, bn = blockIdx.x * 128;
    const int lr8 = lane >> 3;
    const int gs  = ((lane & 7) ^ lr8) * 8;    // global-side swizzle (rows = base8 + lr8)

    v4f acc[2][4] = {};
    for (int k0 = 0; k0 < FEAT; k0 += 64) {
        gload16(A + (size_t)(bm + w * 16 +      lr8) * FEAT + k0 + gs, &As[w * 16][0]);
        gload16(A + (size_t)(bm + w * 16 + 8 +  lr8) * FEAT + k0 + gs, &As[w * 16 + 8][0]);
        gload16(B + (size_t)(bn + w * 32 +      lr8) * FEAT + k0 + gs, &Bs[w * 32][0]);
        gload16(B + (size_t)(bn + w * 32 + 8 +  lr8) * FEAT + k0 + gs, &Bs[w * 32 + 8][0]);
        gload16(B + (size_t)(bn + w * 32 + 16 + lr8) * FEAT + k0 + gs, &Bs[w * 32 + 16][0]);
        gload16(B + (size_t)(bn + w * 32 + 24 + lr8) * FEAT + k0 + gs, &Bs[w * 32 + 24][0]);
        __syncthreads();
#pragma unroll
        for (int kk = 0; kk < 2; kk++) {
            const int fo = ((kk * 4 + quad) ^ (l15 & 7)) * 8;   // un-swizzled frag octet
            v8bf a[2], b[4];
#pragma unroll
            for (int mi = 0; mi < 2; mi++) a[mi] = *(const v8bf*)&As[wm * 32 + mi * 16 + l15][fo];
#pragma unroll
            for (int ni = 0; ni < 4; ni++) b[ni] = *(const v8bf*)&Bs[wn * 64 + ni * 16 + l15][fo];
#pragma unroll
            for (int mi = 0; mi < 2; mi++)
#pragma unroll
                for (int ni = 0; ni < 4; ni++)
                    acc[mi][ni] = __builtin_amdgcn_mfma_f32_16x16x32_bf16(a[mi], b[ni], acc[mi][ni], 0, 0, 0);
        }
        __syncthreads();
    }
    if (bn < 2 * FEAT) {         // Q,K region
#pragma unroll
        for (int mi = 0; mi < 2; mi++)
#pragma unroll
            for (int ni = 0; ni < 4; ni++) {
                int col = bn + wn * 64 + ni * 16 + l15;
#pragma unroll
                for (int r = 0; r < 4; r++) {
                    int row = bm + wm * 32 + mi * 16 + quad * 4 + r;
                    qk[(size_t)row * QK_LD + col] = (__bf16)acc[mi][ni][r];
                }
            }
    } else {                     // V region: transposed packed store vt[col-1536][row]
#pragma unroll
        for (int mi = 0; mi < 2; mi++)
#pragma unroll
            for (int ni = 0; ni < 4; ni++) {
                int col = bn + wn * 64 + ni * 16 + l15 - 2 * FEAT;
                int row = bm + wm * 32 + mi * 16 + quad * 4;
                v4bf pk;
#pragma unroll
                for (int r = 0; r < 4; r++) pk[r] = (__bf16)acc[mi][ni][r];
                *(v4bf*)(vt + (size_t)col * N_TOK + row) = pk;
            }
    }
}

// ---------------------------------------------------------------- attention v8 (R15 best — unchanged)
// S^T, qt=2, per-half PV, PT [4][32][32]; LDS = 32 KB KV + 8 KB PT = 40 KB.
// Grid (16, 12, SPLIT=4) = 768 blocks.
__global__ __launch_bounds__(256, 4) void attention(
        const __bf16* __restrict__ QK, const __bf16* __restrict__ vt,
        __bf16* __restrict__ Opart, float* __restrict__ lpart) {
    __shared__ __bf16 KV[2][2][64][64];   // [buf][K/V][row][64]  32 KB
    __shared__ __bf16 PT[4][32][32];      // per-wave P^T half: [w][q][kv32]  8 KB
    const int t    = threadIdx.x;
    const int lane = t & 63, w = t >> 6;
    const int quad = lane >> 4, l15 = lane & 15;
    const int h = blockIdx.y, s = blockIdx.z;
    const int q0 = blockIdx.x * 128 + w * 32;
    const int sw3 = l15 & 3;              // PT octet swizzle

    v8bf qf[2][2];
#pragma unroll
    for (int qt = 0; qt < 2; qt++) {
        const __bf16* qp = QK + (size_t)(q0 + qt * 16 + l15) * QK_LD + h * DHEAD + quad * 8;
        qf[qt][0] = *(const v8bf*)qp;
        qf[qt][1] = *(const v8bf*)(qp + 32);
    }
    const __bf16* kg = QK + FEAT + h * DHEAD;
    const __bf16* vg = vt + (size_t)(h * DHEAD) * N_TOK;

    v4f o_acc[4][2] = {};                 // [dt][qt]: O^T rows d=quad*4+r, cols q
    float lacc[2] = {0.f, 0.f};

    const int kvbeg = s * KV_PER;
    const int lr8 = lane >> 3;

    auto stage = [&](int b, int kv0) {
#pragma unroll
        for (int i = 0; i < 2; i++) {
            int row = w * 16 + i * 8 + lr8;
            int gsk = (lane & 7) ^ (row & 7);              // global-side swizzle
            gload16(kg + (size_t)(kv0 + row) * QK_LD + gsk * 8, &KV[b][0][w * 16 + i * 8][0]);
            gload16(vg + (size_t)row * N_TOK + kv0 + gsk * 8,   &KV[b][1][w * 16 + i * 8][0]);
        }
    };

    auto step = [&](int b) {
#pragma unroll
        for (int half = 0; half < 2; half++) {
            // ---- S^T for this half's 32 kv rows; exp; write P^T half
#pragma unroll
            for (int kk = 0; kk < 2; kk++) {
                int kvt = half * 2 + kk;
                v8bf kf0 = *(const v8bf*)&KV[b][0][kvt * 16 + l15][((0 + quad) ^ (l15 & 7)) * 8];
                v8bf kf1 = *(const v8bf*)&KV[b][0][kvt * 16 + l15][((4 + quad) ^ (l15 & 7)) * 8];
                const int wcol = ((kk * 2 + (quad >> 1)) ^ sw3) * 8 + (quad & 1) * 4;
#pragma unroll
                for (int qt = 0; qt < 2; qt++) {
                    v4f a = {};
                    a = __builtin_amdgcn_mfma_f32_16x16x32_bf16(kf0, qf[qt][0], a, 0, 0, 0);
                    a = __builtin_amdgcn_mfma_f32_16x16x32_bf16(kf1, qf[qt][1], a, 0, 0, 0);
                    float p0 = __builtin_amdgcn_exp2f(a[0]);
                    float p1 = __builtin_amdgcn_exp2f(a[1]);
                    float p2 = __builtin_amdgcn_exp2f(a[2]);
                    float p3 = __builtin_amdgcn_exp2f(a[3]);
                    lacc[qt] += (p0 + p1) + (p2 + p3);
                    v4bf pk;
                    pk[0] = (__bf16)p0; pk[1] = (__bf16)p1; pk[2] = (__bf16)p2; pk[3] = (__bf16)p3;
                    *(v4bf*)&PT[w][qt * 16 + l15][wcol] = pk;
                }
            }
            // ---- O^T += V^T_half P^T_half (k=32)
            v8bf vf[4], ptf[2];
#pragma unroll
            for (int dt = 0; dt < 4; dt++)
                vf[dt] = *(const v8bf*)&KV[b][1][dt * 16 + l15][((half * 4 + quad) ^ (l15 & 7)) * 8];
#pragma unroll
            for (int qt = 0; qt < 2; qt++)
                ptf[qt] = *(const v8bf*)&PT[w][qt * 16 + l15][(quad ^ sw3) * 8];
#pragma unroll
            for (int dt = 0; dt < 4; dt++)
#pragma unroll
                for (int qt = 0; qt < 2; qt++)
                    o_acc[dt][qt] = __builtin_amdgcn_mfma_f32_16x16x32_bf16(vf[dt], ptf[qt], o_acc[dt][qt], 0, 0, 0);
        }
    };

    stage(0, kvbeg);
    const int TILES = KV_PER / 64;     // 8
    for (int tt = 0; tt < TILES; tt++) {
        __syncthreads();               // buf[tt&1] staged (vmcnt drain at barrier)
        if (tt + 1 < TILES) stage((tt + 1) & 1, kvbeg + (tt + 1) * 64);
        step(tt & 1);
    }

    // ---- epilogue: l-reduce over quads (2 shfls), packed b64 global stores
    __bf16* op = Opart + (size_t)s * XE;
#pragma unroll
    for (int qt = 0; qt < 2; qt++) {
        float l = lacc[qt];
        l += __shfl_xor(l, 16); l += __shfl_xor(l, 32);   // sum the 4 quads (same q)
        float linv = 1.0f / l;
        int q = q0 + qt * 16 + l15;
        if (quad == 0) lpart[((size_t)s * HEADS + h) * N_TOK + q] = l;
#pragma unroll
        for (int dt = 0; dt < 4; dt++) {
            v4bf pk;
#pragma unroll
            for (int r = 0; r < 4; r++) pk[r] = (__bf16)(o_acc[dt][qt][r] * linv);
            *(v4bf*)(op + (size_t)q * FEAT + h * DHEAD + dt * 16 + quad * 4) = pk;
        }
    }
}

// ---------------------------------------------------------------- combine split partials (one pass)
__global__ __launch_bounds__(256) void combine(
        const __bf16* __restrict__ Op, const float* __restrict__ lp, __bf16* __restrict__ Ob) {
    size_t i = ((size_t)blockIdx.x * 256 + threadIdx.x) * 4;
    int row = (int)(i / FEAT), col = (int)(i % FEAT), h = col >> 6;
    float ls[SPLIT], tot = 0.f;
#pragma unroll
    for (int s = 0; s < SPLIT; s++) {
        ls[s] = lp[((size_t)s * HEADS + h) * N_TOK + row];
        tot += ls[s];
    }
    float inv = 1.0f / tot;
    float a0 = 0.f, a1 = 0.f, a2 = 0.f, a3 = 0.f;
#pragma unroll
    for (int s = 0; s < SPLIT; s++) {
        v4bf p = *(const v4bf*)(Op + s * XE + i);
        float wgt = ls[s] * inv;
        a0 += wgt * (float)p[0]; a1 += wgt * (float)p[1];
        a2 += wgt * (float)p[2]; a3 += wgt * (float)p[3];
    }
    v4bf o;
    o[0] = (__bf16)a0; o[1] = (__bf16)a1; o[2] = (__bf16)a2; o[3] = (__bf16)a3;
    *(v4bf*)(Ob + i) = o;
}

// ---------------------------------------------------------------- output proj + residual
// BK=64 (12 iters, half the barriers — mirrors gemm_qkv's proven change). 64x128 tile.
__global__ __launch_bounds__(256) void gemm_out(
        const __bf16* __restrict__ Ob, const __bf16* __restrict__ Wo,
        const float* __restrict__ x, float* __restrict__ Yf) {
    __shared__ __bf16 As[64][64];
    __shared__ __bf16 Bs[128][64];
    const int t    = threadIdx.x;
    const int lane = t & 63, w = t >> 6;
    const int quad = lane >> 4, l15 = lane & 15;
    const int wm = w & 1, wn = w >> 1;
    const int bm = blockIdx.y * 64, bn = blockIdx.x * 128;
    const int lr8 = lane >> 3;
    const int gs  = ((lane & 7) ^ lr8) * 8;    // global-side swizzle

    v4f acc[2][4] = {};
    for (int k0 = 0; k0 < FEAT; k0 += 64) {
        gload16(Ob + (size_t)(bm + w * 16 +      lr8) * FEAT + k0 + gs, &As[w * 16][0]);
        gload16(Ob + (size_t)(bm + w * 16 + 8 +  lr8) * FEAT + k0 + gs, &As[w * 16 + 8][0]);
        gload16(Wo + (size_t)(bn + w * 32 +      lr8) * FEAT + k0 + gs, &Bs[w * 32][0]);
        gload16(Wo + (size_t)(bn + w * 32 + 8 +  lr8) * FEAT + k0 + gs, &Bs[w * 32 + 8][0]);
        gload16(Wo + (size_t)(bn + w * 32 + 16 + lr8) * FEAT + k0 + gs, &Bs[w * 32 + 16][0]);
        gload16(Wo + (size_t)(bn + w * 32 + 24 + lr8) * FEAT + k0 + gs, &Bs[w * 32 + 24][0]);
        __syncthreads();
#pragma unroll
        for (int kk = 0; kk < 2; kk++) {
            const int fo = ((kk * 4 + quad) ^ (l15 & 7)) * 8;   // un-swizzled frag octet
            v8bf a[2], b[4];
#pragma unroll
            for (int mi = 0; mi < 2; mi++) a[mi] = *(const v8bf*)&As[wm * 32 + mi * 16 + l15][fo];
#pragma unroll
            for (int ni = 0; ni < 4; ni++) b[ni] = *(const v8bf*)&Bs[wn * 64 + ni * 16 + l15][fo];
#pragma unroll
            for (int mi = 0; mi < 2; mi++)
#pragma unroll
                for (int ni = 0; ni < 4; ni++)
                    acc[mi][ni] = __builtin_amdgcn_mfma_f32_16x16x32_bf16(a[mi], b[ni], acc[mi][ni], 0, 0, 0);
        }
        __syncthreads();
    }
#pragma unroll
    for (int mi = 0; mi < 2; mi++)
#pragma unroll
        for (int ni = 0; ni < 4; ni++) {
            int col = bn + wn * 64 + ni * 16 + l15;
#pragma unroll
            for (int r = 0; r < 4; r++) {
                int row = bm + wm * 32 + mi * 16 + quad * 4 + r;
                Yf[(size_t)row * FEAT + col] = acc[mi][ni][r] + x[(size_t)row * FEAT + col];
            }
        }
}

// ---------------------------------------------------------------- layernorm
__global__ __launch_bounds__(256) void ln_kernel(
        const float* __restrict__ Y, const float* __restrict__ gamma,
        const float* __restrict__ beta, float* __restrict__ out) {
    __shared__ float sbuf[4];
    const int row = blockIdx.x, t = threadIdx.x;
    const float* y = Y + (size_t)row * FEAT;
    float v0 = y[t], v1 = y[t + 256], v2 = y[t + 512];
    float s = v0 + v1 + v2;
#pragma unroll
    for (int m = 32; m; m >>= 1) s += __shfl_xor(s, m);
    if ((t & 63) == 0) sbuf[t >> 6] = s;
    __syncthreads();
    float mean = (sbuf[0] + sbuf[1] + sbuf[2] + sbuf[3]) * (1.f / FEAT);
    __syncthreads();
    float d0 = v0 - mean, d1 = v1 - mean, d2 = v2 - mean;
    float q = d0 * d0 + d1 * d1 + d2 * d2;
#pragma unroll
    for (int m = 32; m; m >>= 1) q += __shfl_xor(q, m);
    if ((t & 63) == 0) sbuf[t >> 6] = q;
    __syncthreads();
    float var = (sbuf[0] + sbuf[1] + sbuf[2] + sbuf[3]) * (1.f / FEAT);
    float rs = rsqrtf(var + 1e-12f);
    float* o = out + (size_t)row * FEAT;
    o[t]       = d0 * rs * gamma[t]       + beta[t];
    o[t + 256] = d1 * rs * gamma[t + 256] + beta[t + 256];
    o[t + 512] = d2 * rs * gamma[t + 512] + beta[t + 512];
}

// ---------------------------------------------------------------- launch
extern "C" void kernel_launch(void* const* d_in, const int* in_sizes, int n_in,
                              void* d_out, int out_size, void* d_ws, size_t ws_size,
                              hipStream_t stream) {
    const float* x     = (const float*)d_in[0];
    const float* Wq    = (const float*)d_in[1];
    const float* Wk    = (const float*)d_in[2];
    const float* Wv    = (const float*)d_in[3];
    const float* Wo    = (const float*)d_in[4];
    const float* gamma = (const float*)d_in[5];
    const float* beta  = (const float*)d_in[6];
    float* out = (float*)d_out;

    char* ws = (char*)d_ws;
    size_t off = 0;
    auto alloc = [&](size_t bytes) -> void* {
        void* p = ws + off;
        off += (bytes + 255) & ~(size_t)255;
        return p;
    };
    __bf16* xb   = (__bf16*)alloc(XE * 2);                    // dead after gemm_qkv
    __bf16* wqkv = (__bf16*)alloc(3 * WE * 2);                // dead after gemm_qkv
    __bf16* wob  = (__bf16*)alloc(WE * 2);
    __bf16* qk   = (__bf16*)alloc((size_t)N_TOK * QK_LD * 2); // [Q'|K]; dead after attention
    __bf16* vtb  = (__bf16*)alloc((size_t)FEAT * N_TOK * 2);  // V^T; dead after attention
    __bf16* Op   = (__bf16*)alloc(SPLIT * XE * 2);            // normalized split partials
    float*  lp   = (float*)alloc(SPLIT * HEADS * N_TOK * 4);
    __bf16* Ob   = vtb;                                       // aliases vt (dead by combine)
    float*  Yf   = (float*)ws;                                // aliases xb+wqkv (dead by gemm_out)

    cvt_all<<<(int)((XE + 4 * WE) / 4 / 256), 256, 0, stream>>>(x, Wq, Wk, Wv, Wo, xb, wqkv, wob);

    gemm_qkv<<<dim3((QK_LD + FEAT) / 128, N_TOK / 64), 256, 0, stream>>>(xb, wqkv, qk, vtb);

    attention<<<dim3(N_TOK / 128, HEADS, SPLIT), 256, 0, stream>>>(qk, vtb, Op, lp);

    combine<<<(int)(XE / 4 / 256), 256, 0, stream>>>(Op, lp, Ob);

    gemm_out<<<dim3(FEAT / 128, N_TOK / 64), 256, 0, stream>>>(Ob, wob, x, Yf);

    ln_kernel<<<N_TOK, 256, 0, stream>>>(Yf, gamma, beta, out);
}

// Round 22
// 135.329 us; speedup vs baseline: 1.0683x; 1.0009x over previous
//
#include <hip/hip_runtime.h>
#include <hip/hip_bf16.h>
#include <math.h>

#define N_TOK 2048
#define FEAT  768
#define HEADS 12
#define DHEAD 64
#define SPLIT 4
#define KV_PER (N_TOK / SPLIT)   // 512

typedef __bf16 v8bf __attribute__((ext_vector_type(8)));
typedef __bf16 v4bf __attribute__((ext_vector_type(4)));
typedef float  v4f  __attribute__((ext_vector_type(4)));

#define XE ((size_t)N_TOK * FEAT)   // 1572864
#define WE ((size_t)FEAT * FEAT)    //  589824
#define QK_LD 1536                  // [Q'|K] row stride

// fold (1/sqrt(64)) * log2(e) into Wq so softmax is a bare exp2
#define SCALE_FOLD 0.18033688011112042f

// async global->LDS, 16B/lane; LDS dest = wave-uniform base + lane*16 (m104)
__device__ __forceinline__ void gload16(const __bf16* g, __bf16* l) {
    __builtin_amdgcn_global_load_lds(
        (const __attribute__((address_space(1))) unsigned int*)g,
        (__attribute__((address_space(3))) unsigned int*)l, 16, 0, 0);
}

// ---------------------------------------------------------------- convert (1 launch)
__global__ __launch_bounds__(256) void cvt_all(
        const float* __restrict__ x,  const float* __restrict__ Wq,
        const float* __restrict__ Wk, const float* __restrict__ Wv,
        const float* __restrict__ Wo,
        __bf16* __restrict__ xb, __bf16* __restrict__ wqkv, __bf16* __restrict__ wob) {
    size_t i = ((size_t)blockIdx.x * 256 + threadIdx.x) * 4;
    const float* src; __bf16* dst; size_t off; float scale = 1.f;
    if (i < XE)               { src = x;  dst = xb;          off = i; }
    else if (i < XE + WE)     { src = Wq; dst = wqkv;        off = i - XE; scale = SCALE_FOLD; }
    else if (i < XE + 2 * WE) { src = Wk; dst = wqkv + WE;   off = i - XE - WE; }
    else if (i < XE + 3 * WE) { src = Wv; dst = wqkv + 2*WE; off = i - XE - 2*WE; }
    else                      { src = Wo; dst = wob;         off = i - XE - 3*WE; }
    float4 v = *(const float4*)(src + off);
    v4bf o;
    o[0] = (__bf16)(v.x * scale); o[1] = (__bf16)(v.y * scale);
    o[2] = (__bf16)(v.z * scale); o[3] = (__bf16)(v.w * scale);
    *(v4bf*)(dst + off) = o;
}

// ---------------------------------------------------------------- fused QKV GEMM (bf16, gload16)
// 64x128 tile, BK=64 (12 iters). Grid (18, 32) = 576. Global-side octet XOR swizzle.
// QK cols (bn<1536) -> qk row-major stride 1536; V cols -> vt transposed [768][2048].
__global__ __launch_bounds__(256) void gemm_qkv(
        const __bf16* __restrict__ A, const __bf16* __restrict__ B,
        __bf16* __restrict__ qk, __bf16* __restrict__ vt) {
    __shared__ __bf16 As[64][64];
    __shared__ __bf16 Bs[128][64];
    const int t    = threadIdx.x;
    const int lane = t & 63, w = t >> 6;
    const int quad = lane >> 4, l15 = lane & 15;
    const int wm = w & 1, wn = w >> 1;
    const int bm = blockIdx.y * 64, bn = blockIdx.x * 128;
    const int lr8 = lane >> 3;
    const int gs  = ((lane & 7) ^ lr8) * 8;    // global-side swizzle (rows = base8 + lr8)

    v4f acc[2][4] = {};
    for (int k0 = 0; k0 < FEAT; k0 += 64) {
        gload16(A + (size_t)(bm + w * 16 +      lr8) * FEAT + k0 + gs, &As[w * 16][0]);
        gload16(A + (size_t)(bm + w * 16 + 8 +  lr8) * FEAT + k0 + gs, &As[w * 16 + 8][0]);
        gload16(B + (size_t)(bn + w * 32 +      lr8) * FEAT + k0 + gs, &Bs[w * 32][0]);
        gload16(B + (size_t)(bn + w * 32 + 8 +  lr8) * FEAT + k0 + gs, &Bs[w * 32 + 8][0]);
        gload16(B + (size_t)(bn + w * 32 + 16 + lr8) * FEAT + k0 + gs, &Bs[w * 32 + 16][0]);
        gload16(B + (size_t)(bn + w * 32 + 24 + lr8) * FEAT + k0 + gs, &Bs[w * 32 + 24][0]);
        __syncthreads();
#pragma unroll
        for (int kk = 0; kk < 2; kk++) {
            const int fo = ((kk * 4 + quad) ^ (l15 & 7)) * 8;   // un-swizzled frag octet
            v8bf a[2], b[4];
#pragma unroll
            for (int mi = 0; mi < 2; mi++) a[mi] = *(const v8bf*)&As[wm * 32 + mi * 16 + l15][fo];
#pragma unroll
            for (int ni = 0; ni < 4; ni++) b[ni] = *(const v8bf*)&Bs[wn * 64 + ni * 16 + l15][fo];
#pragma unroll
            for (int mi = 0; mi < 2; mi++)
#pragma unroll
                for (int ni = 0; ni < 4; ni++)
                    acc[mi][ni] = __builtin_amdgcn_mfma_f32_16x16x32_bf16(a[mi], b[ni], acc[mi][ni], 0, 0, 0);
        }
        __syncthreads();
    }
    if (bn < 2 * FEAT) {         // Q,K region
#pragma unroll
        for (int mi = 0; mi < 2; mi++)
#pragma unroll
            for (int ni = 0; ni < 4; ni++) {
                int col = bn + wn * 64 + ni * 16 + l15;
#pragma unroll
                for (int r = 0; r < 4; r++) {
                    int row = bm + wm * 32 + mi * 16 + quad * 4 + r;
                    qk[(size_t)row * QK_LD + col] = (__bf16)acc[mi][ni][r];
                }
            }
    } else {                     // V region: transposed packed store vt[col-1536][row]
#pragma unroll
        for (int mi = 0; mi < 2; mi++)
#pragma unroll
            for (int ni = 0; ni < 4; ni++) {
                int col = bn + wn * 64 + ni * 16 + l15 - 2 * FEAT;
                int row = bm + wm * 32 + mi * 16 + quad * 4;
                v4bf pk;
#pragma unroll
                for (int r = 0; r < 4; r++) pk[r] = (__bf16)acc[mi][ni][r];
                *(v4bf*)(vt + (size_t)col * N_TOK + row) = pk;
            }
    }
}

// ---------------------------------------------------------------- attention v8 (best measured)
// S^T, qt=2, per-half PV, PT [4][32][32]; LDS = 32 KB KV + 8 KB PT = 40 KB.
// Grid (16, 12, SPLIT=4) = 768 blocks, 4 blocks/CU.
__global__ __launch_bounds__(256, 4) void attention(
        const __bf16* __restrict__ QK, const __bf16* __restrict__ vt,
        __bf16* __restrict__ Opart, float* __restrict__ lpart) {
    __shared__ __bf16 KV[2][2][64][64];   // [buf][K/V][row][64]  32 KB
    __shared__ __bf16 PT[4][32][32];      // per-wave P^T half: [w][q][kv32]  8 KB
    const int t    = threadIdx.x;
    const int lane = t & 63, w = t >> 6;
    const int quad = lane >> 4, l15 = lane & 15;
    const int h = blockIdx.y, s = blockIdx.z;
    const int q0 = blockIdx.x * 128 + w * 32;
    const int sw3 = l15 & 3;              // PT octet swizzle

    v8bf qf[2][2];
#pragma unroll
    for (int qt = 0; qt < 2; qt++) {
        const __bf16* qp = QK + (size_t)(q0 + qt * 16 + l15) * QK_LD + h * DHEAD + quad * 8;
        qf[qt][0] = *(const v8bf*)qp;
        qf[qt][1] = *(const v8bf*)(qp + 32);
    }
    const __bf16* kg = QK + FEAT + h * DHEAD;
    const __bf16* vg = vt + (size_t)(h * DHEAD) * N_TOK;

    v4f o_acc[4][2] = {};                 // [dt][qt]: O^T rows d=quad*4+r, cols q
    float lacc[2] = {0.f, 0.f};

    const int kvbeg = s * KV_PER;
    const int lr8 = lane >> 3;

    auto stage = [&](int b, int kv0) {
#pragma unroll
        for (int i = 0; i < 2; i++) {
            int row = w * 16 + i * 8 + lr8;
            int gsk = (lane & 7) ^ (row & 7);              // global-side swizzle
            gload16(kg + (size_t)(kv0 + row) * QK_LD + gsk * 8, &KV[b][0][w * 16 + i * 8][0]);
            gload16(vg + (size_t)row * N_TOK + kv0 + gsk * 8,   &KV[b][1][w * 16 + i * 8][0]);
        }
    };

    auto step = [&](int b) {
#pragma unroll
        for (int half = 0; half < 2; half++) {
            // ---- S^T for this half's 32 kv rows; exp; write P^T half
#pragma unroll
            for (int kk = 0; kk < 2; kk++) {
                int kvt = half * 2 + kk;
                v8bf kf0 = *(const v8bf*)&KV[b][0][kvt * 16 + l15][((0 + quad) ^ (l15 & 7)) * 8];
                v8bf kf1 = *(const v8bf*)&KV[b][0][kvt * 16 + l15][((4 + quad) ^ (l15 & 7)) * 8];
                const int wcol = ((kk * 2 + (quad >> 1)) ^ sw3) * 8 + (quad & 1) * 4;
#pragma unroll
                for (int qt = 0; qt < 2; qt++) {
                    v4f a = {};
                    a = __builtin_amdgcn_mfma_f32_16x16x32_bf16(kf0, qf[qt][0], a, 0, 0, 0);
                    a = __builtin_amdgcn_mfma_f32_16x16x32_bf16(kf1, qf[qt][1], a, 0, 0, 0);
                    float p0 = __builtin_amdgcn_exp2f(a[0]);
                    float p1 = __builtin_amdgcn_exp2f(a[1]);
                    float p2 = __builtin_amdgcn_exp2f(a[2]);
                    float p3 = __builtin_amdgcn_exp2f(a[3]);
                    lacc[qt] += (p0 + p1) + (p2 + p3);
                    v4bf pk;
                    pk[0] = (__bf16)p0; pk[1] = (__bf16)p1; pk[2] = (__bf16)p2; pk[3] = (__bf16)p3;
                    *(v4bf*)&PT[w][qt * 16 + l15][wcol] = pk;
                }
            }
            // ---- O^T += V^T_half P^T_half (k=32)
            v8bf vf[4], ptf[2];
#pragma unroll
            for (int dt = 0; dt < 4; dt++)
                vf[dt] = *(const v8bf*)&KV[b][1][dt * 16 + l15][((half * 4 + quad) ^ (l15 & 7)) * 8];
#pragma unroll
            for (int qt = 0; qt < 2; qt++)
                ptf[qt] = *(const v8bf*)&PT[w][qt * 16 + l15][(quad ^ sw3) * 8];
#pragma unroll
            for (int dt = 0; dt < 4; dt++)
#pragma unroll
                for (int qt = 0; qt < 2; qt++)
                    o_acc[dt][qt] = __builtin_amdgcn_mfma_f32_16x16x32_bf16(vf[dt], ptf[qt], o_acc[dt][qt], 0, 0, 0);
        }
    };

    stage(0, kvbeg);
    const int TILES = KV_PER / 64;     // 8
    for (int tt = 0; tt < TILES; tt++) {
        __syncthreads();               // buf[tt&1] staged (vmcnt drain at barrier)
        if (tt + 1 < TILES) stage((tt + 1) & 1, kvbeg + (tt + 1) * 64);
        step(tt & 1);
    }

    // ---- epilogue: l-reduce over quads (2 shfls), packed b64 global stores
    __bf16* op = Opart + (size_t)s * XE;
#pragma unroll
    for (int qt = 0; qt < 2; qt++) {
        float l = lacc[qt];
        l += __shfl_xor(l, 16); l += __shfl_xor(l, 32);   // sum the 4 quads (same q)
        float linv = 1.0f / l;
        int q = q0 + qt * 16 + l15;
        if (quad == 0) lpart[((size_t)s * HEADS + h) * N_TOK + q] = l;
#pragma unroll
        for (int dt = 0; dt < 4; dt++) {
            v4bf pk;
#pragma unroll
            for (int r = 0; r < 4; r++) pk[r] = (__bf16)(o_acc[dt][qt][r] * linv);
            *(v4bf*)(op + (size_t)q * FEAT + h * DHEAD + dt * 16 + quad * 4) = pk;
        }
    }
}

// ---------------------------------------------------------------- combine split partials (one pass)
__global__ __launch_bounds__(256) void combine(
        const __bf16* __restrict__ Op, const float* __restrict__ lp, __bf16* __restrict__ Ob) {
    size_t i = ((size_t)blockIdx.x * 256 + threadIdx.x) * 4;
    int row = (int)(i / FEAT), col = (int)(i % FEAT), h = col >> 6;
    float ls[SPLIT], tot = 0.f;
#pragma unroll
    for (int s = 0; s < SPLIT; s++) {
        ls[s] = lp[((size_t)s * HEADS + h) * N_TOK + row];
        tot += ls[s];
    }
    float inv = 1.0f / tot;
    float a0 = 0.f, a1 = 0.f, a2 = 0.f, a3 = 0.f;
#pragma unroll
    for (int s = 0; s < SPLIT; s++) {
        v4bf p = *(const v4bf*)(Op + s * XE + i);
        float wgt = ls[s] * inv;
        a0 += wgt * (float)p[0]; a1 += wgt * (float)p[1];
        a2 += wgt * (float)p[2]; a3 += wgt * (float)p[3];
    }
    v4bf o;
    o[0] = (__bf16)a0; o[1] = (__bf16)a1; o[2] = (__bf16)a2; o[3] = (__bf16)a3;
    *(v4bf*)(Ob + i) = o;
}

// ---------------------------------------------------------------- output proj + residual
// BK=64 (12 iters). 64x128 tile. A = Ob, B = wob, both via gload16.
__global__ __launch_bounds__(256) void gemm_out(
        const __bf16* __restrict__ Ob, const __bf16* __restrict__ Wo,
        const float* __restrict__ x, float* __restrict__ Yf) {
    __shared__ __bf16 As[64][64];
    __shared__ __bf16 Bs[128][64];
    const int t    = threadIdx.x;
    const int lane = t & 63, w = t >> 6;
    const int quad = lane >> 4, l15 = lane & 15;
    const int wm = w & 1, wn = w >> 1;
    const int bm = blockIdx.y * 64, bn = blockIdx.x * 128;
    const int lr8 = lane >> 3;
    const int gs  = ((lane & 7) ^ lr8) * 8;    // global-side swizzle

    v4f acc[2][4] = {};
    for (int k0 = 0; k0 < FEAT; k0 += 64) {
        gload16(Ob + (size_t)(bm + w * 16 +      lr8) * FEAT + k0 + gs, &As[w * 16][0]);
        gload16(Ob + (size_t)(bm + w * 16 + 8 +  lr8) * FEAT + k0 + gs, &As[w * 16 + 8][0]);
        gload16(Wo + (size_t)(bn + w * 32 +      lr8) * FEAT + k0 + gs, &Bs[w * 32][0]);
        gload16(Wo + (size_t)(bn + w * 32 + 8 +  lr8) * FEAT + k0 + gs, &Bs[w * 32 + 8][0]);
        gload16(Wo + (size_t)(bn + w * 32 + 16 + lr8) * FEAT + k0 + gs, &Bs[w * 32 + 16][0]);
        gload16(Wo + (size_t)(bn + w * 32 + 24 + lr8) * FEAT + k0 + gs, &Bs[w * 32 + 24][0]);
        __syncthreads();
#pragma unroll
        for (int kk = 0; kk < 2; kk++) {
            const int fo = ((kk * 4 + quad) ^ (l15 & 7)) * 8;   // un-swizzled frag octet
            v8bf a[2], b[4];
#pragma unroll
            for (int mi = 0; mi < 2; mi++) a[mi] = *(const v8bf*)&As[wm * 32 + mi * 16 + l15][fo];
#pragma unroll
            for (int ni = 0; ni < 4; ni++) b[ni] = *(const v8bf*)&Bs[wn * 64 + ni * 16 + l15][fo];
#pragma unroll
            for (int mi = 0; mi < 2; mi++)
#pragma unroll
                for (int ni = 0; ni < 4; ni++)
                    acc[mi][ni] = __builtin_amdgcn_mfma_f32_16x16x32_bf16(a[mi], b[ni], acc[mi][ni], 0, 0, 0);
        }
        __syncthreads();
    }
#pragma unroll
    for (int mi = 0; mi < 2; mi++)
#pragma unroll
        for (int ni = 0; ni < 4; ni++) {
            int col = bn + wn * 64 + ni * 16 + l15;
#pragma unroll
            for (int r = 0; r < 4; r++) {
                int row = bm + wm * 32 + mi * 16 + quad * 4 + r;
                Yf[(size_t)row * FEAT + col] = acc[mi][ni][r] + x[(size_t)row * FEAT + col];
            }
        }
}

// ---------------------------------------------------------------- layernorm
__global__ __launch_bounds__(256) void ln_kernel(
        const float* __restrict__ Y, const float* __restrict__ gamma,
        const float* __restrict__ beta, float* __restrict__ out) {
    __shared__ float sbuf[4];
    const int row = blockIdx.x, t = threadIdx.x;
    const float* y = Y + (size_t)row * FEAT;
    float v0 = y[t], v1 = y[t + 256], v2 = y[t + 512];
    float s = v0 + v1 + v2;
#pragma unroll
    for (int m = 32; m; m >>= 1) s += __shfl_xor(s, m);
    if ((t & 63) == 0) sbuf[t >> 6] = s;
    __syncthreads();
    float mean = (sbuf[0] + sbuf[1] + sbuf[2] + sbuf[3]) * (1.f / FEAT);
    __syncthreads();
    float d0 = v0 - mean, d1 = v1 - mean, d2 = v2 - mean;
    float q = d0 * d0 + d1 * d1 + d2 * d2;
#pragma unroll
    for (int m = 32; m; m >>= 1) q += __shfl_xor(q, m);
    if ((t & 63) == 0) sbuf[t >> 6] = q;
    __syncthreads();
    float var = (sbuf[0] + sbuf[1] + sbuf[2] + sbuf[3]) * (1.f / FEAT);
    float rs = rsqrtf(var + 1e-12f);
    float* o = out + (size_t)row * FEAT;
    o[t]       = d0 * rs * gamma[t]       + beta[t];
    o[t + 256] = d1 * rs * gamma[t + 256] + beta[t + 256];
    o[t + 512] = d2 * rs * gamma[t + 512] + beta[t + 512];
}

// ---------------------------------------------------------------- launch
extern "C" void kernel_launch(void* const* d_in, const int* in_sizes, int n_in,
                              void* d_out, int out_size, void* d_ws, size_t ws_size,
                              hipStream_t stream) {
    const float* x     = (const float*)d_in[0];
    const float* Wq    = (const float*)d_in[1];
    const float* Wk    = (const float*)d_in[2];
    const float* Wv    = (const float*)d_in[3];
    const float* Wo    = (const float*)d_in[4];
    const float* gamma = (const float*)d_in[5];
    const float* beta  = (const float*)d_in[6];
    float* out = (float*)d_out;

    char* ws = (char*)d_ws;
    size_t off = 0;
    auto alloc = [&](size_t bytes) -> void* {
        void* p = ws + off;
        off += (bytes + 255) & ~(size_t)255;
        return p;
    };
    __bf16* xb   = (__bf16*)alloc(XE * 2);                    // dead after gemm_qkv
    __bf16* wqkv = (__bf16*)alloc(3 * WE * 2);                // dead after gemm_qkv
    __bf16* wob  = (__bf16*)alloc(WE * 2);
    __bf16* qk   = (__bf16*)alloc((size_t)N_TOK * QK_LD * 2); // [Q'|K]; dead after attention
    __bf16* vtb  = (__bf16*)alloc((size_t)FEAT * N_TOK * 2);  // V^T; dead after attention
    __bf16* Op   = (__bf16*)alloc(SPLIT * XE * 2);            // normalized split partials
    float*  lp   = (float*)alloc(SPLIT * HEADS * N_TOK * 4);
    __bf16* Ob   = vtb;                                       // aliases vt (dead by combine)
    float*  Yf   = (float*)ws;                                // aliases xb+wqkv (dead by gemm_out)

    cvt_all<<<(int)((XE + 4 * WE) / 4 / 256), 256, 0, stream>>>(x, Wq, Wk, Wv, Wo, xb, wqkv, wob);

    gemm_qkv<<<dim3((QK_LD + FEAT) / 128, N_TOK / 64), 256, 0, stream>>>(xb, wqkv, qk, vtb);

    attention<<<dim3(N_TOK / 128, HEADS, SPLIT), 256, 0, stream>>>(qk, vtb, Op, lp);

    combine<<<(int)(XE / 4 / 256), 256, 0, stream>>>(Op, lp, Ob);

    gemm_out<<<dim3(FEAT / 128, N_TOK / 64), 256, 0, stream>>>(Ob, wob, x, Yf);

    ln_kernel<<<N_TOK, 256, 0, stream>>>(Yf, gamma, beta, out);
}